// Round 23
// baseline (142.554 us; speedup 1.0000x reference)
//
#include <hip/hip_runtime.h>

// WL_DiffNet, round 23: BM 64 -> 128 to halve B-weight L2 duplication.
//   Traffic arithmetic (r22 post-mortem): mega is L2-BW-bound; per dispatch
//   gather = 335 MB (irreducible) + B = blocks*384KB = 393 MB (1/BM).
//   BM=128: grid 256, B -> 196 MB (expected -8..-10us of L2 time).
//   LDS 134KB (A_ 64 + N_ 64 + pkL 5) -> 1 block/CU, 8 waves;
//   launch_bounds(512,2) -> VGPR cap 256 (acc[8][2] spill-free).
//   r22 barrier order kept: pk -> tiny barrier -> async F stage + B prefetch
//   -> gather (drain hides here) -> ONE barrier -> barrier-free phase-1.
// Math order unchanged -> absmax must stay 0.03125.

#define BB 64
#define NN 512
#define MAXNB 10
#define HH 256
#define ROWS (BB*NN)   // 32768
#define BM 128         // rows per block
#define ZROW 32768     // zero row index in G/Hb2 buffers

typedef _Float16 f16x8 __attribute__((ext_vector_type(8)));
typedef _Float16 h2 __attribute__((ext_vector_type(2)));
typedef __attribute__((ext_vector_type(4))) float f32x4;
typedef unsigned short u16;
typedef unsigned int u32;
typedef __attribute__((address_space(3))) u32 lds_u32;
typedef __attribute__((address_space(1))) const u32 glb_u32;

union U32H2 { u32 u; h2 h; };

__device__ __forceinline__ u16 f2h(float f) {   // rne f32->f16
    union { _Float16 h; u16 u; } v; v.h = (_Float16)f; return v.u;
}
__device__ __forceinline__ void gl16(const u16* g, u16* l) {
    __builtin_amdgcn_global_load_lds((glb_u32*)g, (lds_u32*)l, 16, 0, 0);
}
// XCD-bijective swizzle (nwg % 8 == 0)
__device__ __forceinline__ int xcd_swz(int bid, int nwg) {
    return (bid & 7) * (nwg >> 3) + (bid >> 3);
}

// ---- prep: hb2 | pkk | castk | wpk1 | wpk2 | zrow+out-zero ---------------
// grid 14401 x 256

__global__ __launch_bounds__(256) void prep(const float* __restrict__ bond,
                                            const float* __restrict__ W2,
                                            const float* __restrict__ b2,
                                            u16* __restrict__ Hb2,
                                            const int* __restrict__ agr,
                                            const int* __restrict__ bgr,
                                            const int* __restrict__ nnb,
                                            u32* __restrict__ pk,
                                            const float* __restrict__ af32,
                                            u16* __restrict__ f0,
                                            const float* __restrict__ W1,
                                            u16* __restrict__ Wp1,
                                            u16* __restrict__ Wp2,
                                            u16* __restrict__ G0,
                                            u16* __restrict__ G1,
                                            float* __restrict__ osum) {
    int b = blockIdx.x, tid = threadIdx.x;
    if (b < 4096) {                       // hb2: rows b*8 .. +8
        int c = tid, r0 = b * 8;
        float w[5];
#pragma unroll
        for (int f = 0; f < 5; ++f) w[f] = W2[(size_t)(HH + f) * HH + c];
        float bb = b2[c];
        for (int r = r0; r < r0 + 8; ++r) {
            float s = bb;
#pragma unroll
            for (int f = 0; f < 5; ++f) s += bond[r * 5 + f] * w[f];
            Hb2[(size_t)r * HH + c] = f2h(s);
        }
    } else if (b < 5376) {                // pkk: t < 327680
        int t = (b - 4096) * 256 + tid;
        int r = t / 10, k = t - r * 10;
        int brow = (r >> 9) << 9;
        bool valid = (k < nnb[r]);
        u32 pA = valid ? (u32)(brow + agr[t * 2 + 1]) : (u32)ZROW;
        u32 pB = valid ? (u32)(brow + bgr[t * 2 + 1]) : (u32)ZROW;
        pk[t] = pA | (pB << 16);
    } else if (b < 13568) {               // castk: 8192 blocks, 4 f32/thread
        int i = (b - 5376) * 256 + tid;
        float4 v = ((const float4*)af32)[i];
        u32 a = f2h(v.x) | ((u32)f2h(v.y) << 16);
        u32 c = f2h(v.z) | ((u32)f2h(v.w) << 16);
        ((uint2*)f0)[i] = make_uint2(a, c);
    } else if (b < 14080) {               // wpk1: W1 [512x256] -> Wp1
        int o = (b - 13568) * 256 + tid;
        int e = o & 7, lane = (o >> 3) & 63, nq = (o >> 9) & 15, kt = o >> 13;
        int k = kt * 32 + (lane >> 4) * 8 + e;
        int n = nq * 16 + (lane & 15);
        Wp1[o] = f2h(W1[(size_t)k * HH + n]);
    } else if (b < 14336) {               // wpk2: W2a [256x256] -> Wp2
        int o = (b - 14080) * 256 + tid;
        int e = o & 7, lane = (o >> 3) & 63, nq = (o >> 9) & 15, kt = o >> 13;
        int k = kt * 32 + (lane >> 4) * 8 + e;
        int n = nq * 16 + (lane & 15);
        Wp2[o] = f2h(W2[(size_t)k * HH + n]);
    } else if (b == 14336) {              // zrow
        G0[(size_t)ZROW * 256 + tid] = 0;
        G1[(size_t)ZROW * 256 + tid] = 0;
        Hb2[(size_t)ZROW * 256 + tid] = 0;
    } else {                              // zero d_out: 64 blocks
        osum[(b - 14337) * 256 + tid] = 0.f;
    }
}

// ---- mega: fused gather + [F|N]@W1 + F'@W2a, BM=128 ----------------------
// 512 thr, 8 waves; wave wc owns cols wc*32..+32, all 128 rows.
// LDS 133.5KB: A_ 64KB (F -> F') + N_ 64KB (N -> G') + pkL 5KB. 1 block/CU.

__global__ __launch_bounds__(512, 2) void mega(const u16* __restrict__ Fh,
                                               const u16* __restrict__ Gall,
                                               const u16* __restrict__ Hall,
                                               const u32* __restrict__ pk,
                                               const u16* __restrict__ Wp1,
                                               const float* __restrict__ b1,
                                               const u16* __restrict__ Wp2,
                                               u16* __restrict__ Fout,
                                               u16* __restrict__ Gout,
                                               float* __restrict__ osum) {
    __shared__ u16 A_[BM * 256];   // 64KB
    __shared__ u16 N_[BM * 256];   // 64KB
    __shared__ u32 pkL[1280];      // 5KB (exact; 5 x 1KB gl16)

    int tid = threadIdx.x;
    int base = xcd_swz(blockIdx.x, gridDim.x) * BM;
    int lane = tid & 63, wid = tid >> 6;
    int wc = wid, m = lane & 15, g = lane >> 4;

    // (1) pk stage behind its own tiny barrier
    if (Wp1) {
        if (wid < 5)
            gl16((const u16*)(pk + (size_t)base * 10) + wid * 512 + lane * 8,
                 (u16*)pkL + wid * 512);
        __syncthreads();   // pkL ready (5KB drain)
    }

    // (2) F stage (64KB) + B prefetch issued async; drain hides under gather
#pragma unroll
    for (int q = 0; q < 8; ++q) {
        int c = (wid * 8 + q) * 64 + lane;
        int r = c >> 5, ph = c & 31;
        gl16(Fh + (size_t)(base + r) * 256 + (ph ^ (r & 7)) * 8,
             A_ + (wid * 8 + q) * 512);
    }
    uint4 breg[2];
    {
        const u16* Wp0 = Wp1 ? Wp1 : Wp2;
#pragma unroll
        for (int j = 0; j < 2; ++j)
            breg[j] = *(const uint4*)(Wp0 + ((size_t)(wc * 2 + j) * 64 + lane) * 8);
    }

    if (Wp1) {
        // ---- gather: rows wid*16..+16; pk wave-uniform -> readfirstlane --
        const uint2* Gb = (const uint2*)Gall;
        const uint2* Hb = (const uint2*)Hall;
        h2 zz = (h2)(_Float16)0;
        for (int i = 0; i < 16; ++i) {
            int r = wid * 16 + i;
            uint2 ga[10], hb[10];
#pragma unroll
            for (int k = 0; k < MAXNB; ++k) {
                u32 p = (u32)__builtin_amdgcn_readfirstlane((int)pkL[r * 10 + k]);
                ga[k] = Gb[(size_t)(p & 0xffffu) * 64 + lane];
                hb[k] = Hb[(size_t)(p >> 16) * 64 + lane];
            }
            h2 accA = zz, accB = zz;
#pragma unroll
            for (int k = 0; k < MAXNB; ++k) {
                U32H2 ax{ga[k].x}, ay{ga[k].y}, cx{hb[k].x}, cy{hb[k].y};
                accA += __builtin_elementwise_max(ax.h + cx.h, zz);
                accB += __builtin_elementwise_max(ay.h + cy.h, zz);
            }
            U32H2 oa, ob; oa.h = accA; ob.h = accB;
            int s16 = (lane >> 1) ^ (r & 7);
            *(uint2*)(N_ + r * 256 + s16 * 8 + (lane & 1) * 4) =
                make_uint2(oa.u, ob.u);
        }
    }

    __syncthreads();   // A_ staged AND all N_ writes visible (one barrier)

    if (Wp1) {
        f32x4 acc[8][2];
#pragma unroll
        for (int mi = 0; mi < 8; ++mi)
#pragma unroll
            for (int j = 0; j < 2; ++j) acc[mi][j] = (f32x4){0.f, 0.f, 0.f, 0.f};

        // ---- phase-1: kt 0..15, barrier-free (A_ for kt<8, N_ for kt>=8)
        for (int kt = 0; kt < 16; ++kt) {
            f16x8 bcur[2];
            bcur[0] = *(f16x8*)&breg[0];
            bcur[1] = *(f16x8*)&breg[1];
            if (kt < 15) {
#pragma unroll
                for (int j = 0; j < 2; ++j)
                    breg[j] = *(const uint4*)(Wp1 +
                        ((size_t)((kt + 1) * 16 + wc * 2 + j) * 64 + lane) * 8);
            } else if (Gout) {
#pragma unroll
                for (int j = 0; j < 2; ++j)
                    breg[j] = *(const uint4*)(Wp2 +
                        ((size_t)(wc * 2 + j) * 64 + lane) * 8);
            }
            const u16* Ar = (kt < 8) ? A_ : N_;
            int asl = (kt & 7) * 4 + g;
#pragma unroll
            for (int mi = 0; mi < 8; ++mi) {
                int r = mi * 16 + m;
                f16x8 af = *(const f16x8*)(Ar + r * 256 + ((asl ^ (r & 7)) * 8));
                acc[mi][0] = __builtin_amdgcn_mfma_f32_16x16x32_f16(
                    af, bcur[0], acc[mi][0], 0, 0, 0);
                acc[mi][1] = __builtin_amdgcn_mfma_f32_16x16x32_f16(
                    af, bcur[1], acc[mi][1], 0, 0, 0);
            }
        }

        if (osum) {
            // final depth: relu(acc+b1), in-register row-sum, reduce over g,
            // one atomicAdd per (block, col). 128 rows all in one batch.
            int b = base >> 9;
#pragma unroll
            for (int j = 0; j < 2; ++j) {
                int col = wc * 32 + j * 16 + m;
                float bb = b1[col];
                float s = 0.f;
#pragma unroll
                for (int mi = 0; mi < 8; ++mi)
#pragma unroll
                    for (int rr = 0; rr < 4; ++rr)
                        s += fmaxf(acc[mi][j][rr] + bb, 0.f);
                s += __shfl_xor(s, 16);
                s += __shfl_xor(s, 32);
                if (g == 0) atomicAdd(osum + b * 256 + col, s);
            }
            return;
        }

        __syncthreads();   // B2: all waves done reading A_/N_

        // F' = relu(acc+b1) -> A_ (F dead)
#pragma unroll
        for (int mi = 0; mi < 8; ++mi)
#pragma unroll
            for (int j = 0; j < 2; ++j) {
                int col = wc * 32 + j * 16 + m;
                float bb = b1[col];
#pragma unroll
                for (int rr = 0; rr < 4; ++rr) {
                    int r = mi * 16 + g * 4 + rr;
                    A_[r * 256 + ((col >> 3) ^ (r & 7)) * 8 + (col & 7)] =
                        f2h(fmaxf(acc[mi][j][rr] + bb, 0.f));
                }
            }
        __syncthreads();   // B3: F' visible

        // coalesced F' store (4096 uint4 chunks, 8 per thread)
#pragma unroll
        for (int i = 0; i < 8; ++i) {
            int c = tid + i * 512;
            int r = c >> 5, ph = c & 31;
            uint4 v = ((const uint4*)A_)[r * 32 + ph];
            ((uint4*)(Fout + (size_t)(base + r) * 256))[ph ^ (r & 7)] = v;
        }
    }
    // (skip-mode: single barrier done; breg holds Wp2 kt0)

    if (!Gout) return;

    // phase-2: G' = A_(F' or F) @ W2a, K=256, 8 kt, barrier-free
    f32x4 gacc[8][2];
#pragma unroll
    for (int mi = 0; mi < 8; ++mi)
#pragma unroll
        for (int j = 0; j < 2; ++j) gacc[mi][j] = (f32x4){0.f, 0.f, 0.f, 0.f};

    for (int kt = 0; kt < 8; ++kt) {
        f16x8 bcur[2];
        bcur[0] = *(f16x8*)&breg[0];
        bcur[1] = *(f16x8*)&breg[1];
        if (kt < 7) {
#pragma unroll
            for (int j = 0; j < 2; ++j)
                breg[j] = *(const uint4*)(Wp2 +
                    ((size_t)((kt + 1) * 16 + wc * 2 + j) * 64 + lane) * 8);
        }
        int asl = kt * 4 + g;
#pragma unroll
        for (int mi = 0; mi < 8; ++mi) {
            int r = mi * 16 + m;
            f16x8 af = *(const f16x8*)(A_ + r * 256 + ((asl ^ (r & 7)) * 8));
            gacc[mi][0] = __builtin_amdgcn_mfma_f32_16x16x32_f16(
                af, bcur[0], gacc[mi][0], 0, 0, 0);
            gacc[mi][1] = __builtin_amdgcn_mfma_f32_16x16x32_f16(
                af, bcur[1], gacc[mi][1], 0, 0, 0);
        }
    }

    // G' -> N_ bounce (N dead), then coalesced store
#pragma unroll
    for (int mi = 0; mi < 8; ++mi)
#pragma unroll
        for (int j = 0; j < 2; ++j) {
            int col = wc * 32 + j * 16 + m;
#pragma unroll
            for (int rr = 0; rr < 4; ++rr) {
                int r = mi * 16 + g * 4 + rr;
                N_[r * 256 + ((col >> 3) ^ (r & 7)) * 8 + (col & 7)] =
                    f2h(gacc[mi][j][rr]);
            }
        }
    __syncthreads();   // B4: G' visible
#pragma unroll
    for (int i = 0; i < 8; ++i) {
        int c = tid + i * 512;
        int r = c >> 5, ph = c & 31;
        uint4 v = ((const uint4*)N_)[r * 32 + ph];
        ((uint4*)(Gout + (size_t)(base + r) * 256))[ph ^ (r & 7)] = v;
    }
}

extern "C" void kernel_launch(void* const* d_in, const int* in_sizes, int n_in,
                              void* d_out, int out_size, void* d_ws, size_t ws_size,
                              hipStream_t stream) {
    const float* input_bond    = (const float*)d_in[1];
    const int*   atom_graph    = (const int*)d_in[2];
    const int*   bond_graph    = (const int*)d_in[3];
    const int*   num_nbs       = (const int*)d_in[4];
    const float* atom_features = (const float*)d_in[5];
    const float* W2 = (const float*)d_in[6];
    const float* b2 = (const float*)d_in[7];
    const float* W1 = (const float*)d_in[8];
    const float* b1 = (const float*)d_in[9];
    float* out = (float*)d_out;

    char* w = (char*)d_ws;
    u16* f0  = (u16*)w;                          // 16MB
    u16* f1  = (u16*)(w + ((size_t)16 << 20));   // 16MB
    u16* G0  = (u16*)(w + ((size_t)32 << 20));   // 16MB + zero row
    u16* G1  = (u16*)(w + ((size_t)49 << 20));   // 16MB + zero row
    u16* Hb2 = (u16*)(w + ((size_t)66 << 20));   // 16MB + zero row
    u16* Wp1 = (u16*)(w + ((size_t)83 << 20));            // 256KB
    u16* Wp2 = (u16*)(w + ((size_t)83 << 20) + (512 << 10)); // 128KB
    u32* pk  = (u32*)(w + ((size_t)84 << 20));   // 1.25MB

    prep<<<14401, 256, 0, stream>>>(input_bond, W2, b2, Hb2, atom_graph,
                                    bond_graph, num_nbs, pk, atom_features,
                                    f0, W1, Wp1, Wp2, G0, G1, out);

    // G0 = F0 @ W2a  (skip-mode)
    mega<<<ROWS / BM, 512, 0, stream>>>(f0, nullptr, nullptr, nullptr,
                                        nullptr, nullptr, Wp2, nullptr, G0,
                                        nullptr);
    // depth 0..2 (G ping-pong; final depth: fused row-sum -> d_out)
    mega<<<ROWS / BM, 512, 0, stream>>>(f0, G0, Hb2, pk, Wp1, b1, Wp2, f1, G1,
                                        nullptr);
    mega<<<ROWS / BM, 512, 0, stream>>>(f1, G1, Hb2, pk, Wp1, b1, Wp2, f0, G0,
                                        nullptr);
    mega<<<ROWS / BM, 512, 0, stream>>>(f0, G0, Hb2, pk, Wp1, b1, Wp2, nullptr,
                                        nullptr, out);
}

// Round 24
// 136.877 us; speedup vs baseline: 1.0415x; 1.0415x over previous
//
#include <hip/hip_runtime.h>

// WL_DiffNet, round 24: REVERT to round-21 exactly (measured best: 136.4us,
// absmax 0.03125). r23 (BM=128) regressed via occupancy collapse; BM=64 is
// confirmed optimal from both directions (r18 BM=32 also regressed).
//   Structure: fused per-depth mega (BM=64, fp16, 8 waves x 32-col tiles);
//   pk+F staged via global_load_lds; fragment-major weights reg-prefetched;
//   barrier0 -> gather (batched row loads) -> phase-1a (A_) -> barrier1 ->
//   phase-1b (N_) -> epilogue (F'+phase-2 G' | final fused row-sum atomics).

#define BB 64
#define NN 512
#define MAXNB 10
#define HH 256
#define ROWS (BB*NN)   // 32768
#define BM 64          // rows per block
#define ZROW 32768     // zero row index in G/Hb2 buffers

typedef _Float16 f16x8 __attribute__((ext_vector_type(8)));
typedef _Float16 h2 __attribute__((ext_vector_type(2)));
typedef __attribute__((ext_vector_type(4))) float f32x4;
typedef unsigned short u16;
typedef unsigned int u32;
typedef __attribute__((address_space(3))) u32 lds_u32;
typedef __attribute__((address_space(1))) const u32 glb_u32;

union U32H2 { u32 u; h2 h; };

__device__ __forceinline__ u16 f2h(float f) {   // rne f32->f16
    union { _Float16 h; u16 u; } v; v.h = (_Float16)f; return v.u;
}
__device__ __forceinline__ void gl16(const u16* g, u16* l) {
    __builtin_amdgcn_global_load_lds((glb_u32*)g, (lds_u32*)l, 16, 0, 0);
}
// XCD-bijective swizzle (nwg % 8 == 0)
__device__ __forceinline__ int xcd_swz(int bid, int nwg) {
    return (bid & 7) * (nwg >> 3) + (bid >> 3);
}

// ---- prep: hb2 | pkk | castk | wpk1 | wpk2 | zrow+out-zero ---------------
// grid 14401 x 256

__global__ __launch_bounds__(256) void prep(const float* __restrict__ bond,
                                            const float* __restrict__ W2,
                                            const float* __restrict__ b2,
                                            u16* __restrict__ Hb2,
                                            const int* __restrict__ agr,
                                            const int* __restrict__ bgr,
                                            const int* __restrict__ nnb,
                                            u32* __restrict__ pk,
                                            const float* __restrict__ af32,
                                            u16* __restrict__ f0,
                                            const float* __restrict__ W1,
                                            u16* __restrict__ Wp1,
                                            u16* __restrict__ Wp2,
                                            u16* __restrict__ G0,
                                            u16* __restrict__ G1,
                                            float* __restrict__ osum) {
    int b = blockIdx.x, tid = threadIdx.x;
    if (b < 4096) {                       // hb2: rows b*8 .. +8
        int c = tid, r0 = b * 8;
        float w[5];
#pragma unroll
        for (int f = 0; f < 5; ++f) w[f] = W2[(size_t)(HH + f) * HH + c];
        float bb = b2[c];
        for (int r = r0; r < r0 + 8; ++r) {
            float s = bb;
#pragma unroll
            for (int f = 0; f < 5; ++f) s += bond[r * 5 + f] * w[f];
            Hb2[(size_t)r * HH + c] = f2h(s);
        }
    } else if (b < 5376) {                // pkk: t < 327680
        int t = (b - 4096) * 256 + tid;
        int r = t / 10, k = t - r * 10;
        int brow = (r >> 9) << 9;
        bool valid = (k < nnb[r]);
        u32 pA = valid ? (u32)(brow + agr[t * 2 + 1]) : (u32)ZROW;
        u32 pB = valid ? (u32)(brow + bgr[t * 2 + 1]) : (u32)ZROW;
        pk[t] = pA | (pB << 16);
    } else if (b < 13568) {               // castk: 8192 blocks, 4 f32/thread
        int i = (b - 5376) * 256 + tid;
        float4 v = ((const float4*)af32)[i];
        u32 a = f2h(v.x) | ((u32)f2h(v.y) << 16);
        u32 c = f2h(v.z) | ((u32)f2h(v.w) << 16);
        ((uint2*)f0)[i] = make_uint2(a, c);
    } else if (b < 14080) {               // wpk1: W1 [512x256] -> Wp1
        int o = (b - 13568) * 256 + tid;
        int e = o & 7, lane = (o >> 3) & 63, nq = (o >> 9) & 15, kt = o >> 13;
        int k = kt * 32 + (lane >> 4) * 8 + e;
        int n = nq * 16 + (lane & 15);
        Wp1[o] = f2h(W1[(size_t)k * HH + n]);
    } else if (b < 14336) {               // wpk2: W2a [256x256] -> Wp2
        int o = (b - 14080) * 256 + tid;
        int e = o & 7, lane = (o >> 3) & 63, nq = (o >> 9) & 15, kt = o >> 13;
        int k = kt * 32 + (lane >> 4) * 8 + e;
        int n = nq * 16 + (lane & 15);
        Wp2[o] = f2h(W2[(size_t)k * HH + n]);
    } else if (b == 14336) {              // zrow
        G0[(size_t)ZROW * 256 + tid] = 0;
        G1[(size_t)ZROW * 256 + tid] = 0;
        Hb2[(size_t)ZROW * 256 + tid] = 0;
    } else {                              // zero d_out: 64 blocks
        osum[(b - 14337) * 256 + tid] = 0.f;
    }
}

// ---- mega: fused gather + [F|N]@W1 + F'@W2a ------------------------------
// 512 thr, 8 waves; wave wc owns cols wc*32..+32, all 64 rows.
// LDS: A_ 32KB (F -> F') + N_ 32KB (N -> G') + pkL 3KB.

__global__ __launch_bounds__(512, 4) void mega(const u16* __restrict__ Fh,
                                               const u16* __restrict__ Gall,
                                               const u16* __restrict__ Hall,
                                               const u32* __restrict__ pk,
                                               const u16* __restrict__ Wp1,
                                               const float* __restrict__ b1,
                                               const u16* __restrict__ Wp2,
                                               u16* __restrict__ Fout,
                                               u16* __restrict__ Gout,
                                               float* __restrict__ osum) {
    __shared__ u16 A_[BM * 256];   // 32KB
    __shared__ u16 N_[BM * 256];   // 32KB
    __shared__ u32 pkL[768];       // 3KB (640 used; staged in 3x1KB gl16)

    int tid = threadIdx.x;
    int base = xcd_swz(blockIdx.x, gridDim.x) * BM;
    int lane = tid & 63, wid = tid >> 6;
    int wc = wid, m = lane & 15, g = lane >> 4;

    // stage F -> A_ (async, pre-swizzled PER-LANE source / linear dest)
#pragma unroll
    for (int q = 0; q < 4; ++q) {
        int c = (wid * 4 + q) * 64 + lane;
        int r = c >> 5, ph = c & 31;
        gl16(Fh + (size_t)(base + r) * 256 + (ph ^ (r & 7)) * 8,
             A_ + (wid * 4 + q) * 512);
    }
    // stage pk slice -> pkL (waves 0..2, 1KB each; per-lane source)
    if (Wp1 && wid < 3)
        gl16((const u16*)(pk + (size_t)base * 10) + wid * 512 + lane * 8,
             (u16*)pkL + wid * 512);

    uint4 breg[2];
    // prefetch B kt0 (latency absorbed by barrier0's drain)
    {
        const u16* Wp0 = Wp1 ? Wp1 : Wp2;
#pragma unroll
        for (int j = 0; j < 2; ++j)
            breg[j] = *(const uint4*)(Wp0 + ((size_t)(wc * 2 + j) * 64 + lane) * 8);
    }
    __syncthreads();   // barrier0: A_ + pkL staged

    if (Wp1) {
        // ---- gather: rows wid*8..+8; batched row loads (>=20 in flight) --
        const uint2* Gb = (const uint2*)Gall;
        const uint2* Hb = (const uint2*)Hall;
        h2 zz = (h2)(_Float16)0;
#pragma unroll
        for (int i = 0; i < 8; ++i) {
            int r = wid * 8 + i;
            uint2 ga[10], hb[10];
#pragma unroll
            for (int k = 0; k < MAXNB; ++k) {
                u32 p = (u32)__builtin_amdgcn_readfirstlane((int)pkL[r * 10 + k]);
                ga[k] = Gb[(size_t)(p & 0xffffu) * 64 + lane];
                hb[k] = Hb[(size_t)(p >> 16) * 64 + lane];
            }
            h2 accA = zz, accB = zz;
#pragma unroll
            for (int k = 0; k < MAXNB; ++k) {
                U32H2 ax{ga[k].x}, ay{ga[k].y}, cx{hb[k].x}, cy{hb[k].y};
                accA += __builtin_elementwise_max(ax.h + cx.h, zz);
                accB += __builtin_elementwise_max(ay.h + cy.h, zz);
            }
            U32H2 oa, ob; oa.h = accA; ob.h = accB;
            int s16 = (lane >> 1) ^ (r & 7);
            *(uint2*)(N_ + r * 256 + s16 * 8 + (lane & 1) * 4) =
                make_uint2(oa.u, ob.u);
        }

        f32x4 acc[4][2];
#pragma unroll
        for (int mi = 0; mi < 4; ++mi)
#pragma unroll
            for (int j = 0; j < 2; ++j) acc[mi][j] = (f32x4){0.f, 0.f, 0.f, 0.f};

        // ---- phase-1a: kt 0..7 reads A_ ONLY -- no barrier after gather
        for (int kt = 0; kt < 8; ++kt) {
            f16x8 bcur[2];
            bcur[0] = *(f16x8*)&breg[0];
            bcur[1] = *(f16x8*)&breg[1];
#pragma unroll
            for (int j = 0; j < 2; ++j)
                breg[j] = *(const uint4*)(Wp1 +
                    ((size_t)((kt + 1) * 16 + wc * 2 + j) * 64 + lane) * 8);
            int asl = kt * 4 + g;
            f16x8 af[4];
#pragma unroll
            for (int mi = 0; mi < 4; ++mi) {
                int r = mi * 16 + m;
                af[mi] = *(const f16x8*)(A_ + r * 256 + ((asl ^ (r & 7)) * 8));
            }
#pragma unroll
            for (int mi = 0; mi < 4; ++mi)
#pragma unroll
                for (int j = 0; j < 2; ++j)
                    acc[mi][j] = __builtin_amdgcn_mfma_f32_16x16x32_f16(
                        af[mi], bcur[j], acc[mi][j], 0, 0, 0);
        }
        __syncthreads();   // barrier1: all N_ writes visible

        // ---- phase-1b: kt 8..15 reads N_
        for (int kt = 8; kt < 16; ++kt) {
            f16x8 bcur[2];
            bcur[0] = *(f16x8*)&breg[0];
            bcur[1] = *(f16x8*)&breg[1];
            if (kt < 15) {
#pragma unroll
                for (int j = 0; j < 2; ++j)
                    breg[j] = *(const uint4*)(Wp1 +
                        ((size_t)((kt + 1) * 16 + wc * 2 + j) * 64 + lane) * 8);
            } else if (Gout) {
#pragma unroll
                for (int j = 0; j < 2; ++j)
                    breg[j] = *(const uint4*)(Wp2 +
                        ((size_t)(wc * 2 + j) * 64 + lane) * 8);
            }
            int asl = (kt & 7) * 4 + g;
            f16x8 af[4];
#pragma unroll
            for (int mi = 0; mi < 4; ++mi) {
                int r = mi * 16 + m;
                af[mi] = *(const f16x8*)(N_ + r * 256 + ((asl ^ (r & 7)) * 8));
            }
#pragma unroll
            for (int mi = 0; mi < 4; ++mi)
#pragma unroll
                for (int j = 0; j < 2; ++j)
                    acc[mi][j] = __builtin_amdgcn_mfma_f32_16x16x32_f16(
                        af[mi], bcur[j], acc[mi][j], 0, 0, 0);
        }

        if (osum) {
            // final depth: relu(acc+b1), in-register row-sum, reduce over g,
            // one atomicAdd per (block, col). No F' store, no phase-2.
            int b = base >> 9;
#pragma unroll
            for (int j = 0; j < 2; ++j) {
                int col = wc * 32 + j * 16 + m;
                float bb = b1[col];
                float s = 0.f;
#pragma unroll
                for (int mi = 0; mi < 4; ++mi)
#pragma unroll
                    for (int rr = 0; rr < 4; ++rr)
                        s += fmaxf(acc[mi][j][rr] + bb, 0.f);
                s += __shfl_xor(s, 16);
                s += __shfl_xor(s, 32);
                if (g == 0) atomicAdd(osum + b * 256 + col, s);
            }
            return;
        }

        __syncthreads();   // B2: all waves done reading A_/N_

        // F' = relu(acc+b1) -> A_ (F dead)
#pragma unroll
        for (int mi = 0; mi < 4; ++mi)
#pragma unroll
            for (int j = 0; j < 2; ++j) {
                int col = wc * 32 + j * 16 + m;
                float bb = b1[col];
#pragma unroll
                for (int rr = 0; rr < 4; ++rr) {
                    int r = mi * 16 + g * 4 + rr;
                    A_[r * 256 + ((col >> 3) ^ (r & 7)) * 8 + (col & 7)] =
                        f2h(fmaxf(acc[mi][j][rr] + bb, 0.f));
                }
            }
        __syncthreads();   // B3: F' visible

        // coalesced F' store
#pragma unroll
        for (int i = 0; i < 4; ++i) {
            int c = tid + i * 512;
            int r = c >> 5, ph = c & 31;
            uint4 v = ((const uint4*)A_)[r * 32 + ph];
            ((uint4*)(Fout + (size_t)(base + r) * 256))[ph ^ (r & 7)] = v;
        }
    }
    // (skip-mode: barrier0 already done; breg holds Wp2 kt0)

    if (!Gout) return;

    // phase-2: G' = A_(F' or F) @ W2a, K=256, 8 kt, barrier-free
    f32x4 gacc[4][2];
#pragma unroll
    for (int mi = 0; mi < 4; ++mi)
#pragma unroll
        for (int j = 0; j < 2; ++j) gacc[mi][j] = (f32x4){0.f, 0.f, 0.f, 0.f};

    for (int kt = 0; kt < 8; ++kt) {
        f16x8 bcur[2];
        bcur[0] = *(f16x8*)&breg[0];
        bcur[1] = *(f16x8*)&breg[1];
        if (kt < 7) {
#pragma unroll
            for (int j = 0; j < 2; ++j)
                breg[j] = *(const uint4*)(Wp2 +
                    ((size_t)((kt + 1) * 16 + wc * 2 + j) * 64 + lane) * 8);
        }
        int asl = kt * 4 + g;
        f16x8 af[4];
#pragma unroll
        for (int mi = 0; mi < 4; ++mi) {
            int r = mi * 16 + m;
            af[mi] = *(const f16x8*)(A_ + r * 256 + ((asl ^ (r & 7)) * 8));
        }
#pragma unroll
        for (int mi = 0; mi < 4; ++mi)
#pragma unroll
            for (int j = 0; j < 2; ++j)
                gacc[mi][j] = __builtin_amdgcn_mfma_f32_16x16x32_f16(
                    af[mi], bcur[j], gacc[mi][j], 0, 0, 0);
    }

    // G' -> N_ bounce (N dead), then coalesced store
#pragma unroll
    for (int mi = 0; mi < 4; ++mi)
#pragma unroll
        for (int j = 0; j < 2; ++j) {
            int col = wc * 32 + j * 16 + m;
#pragma unroll
            for (int rr = 0; rr < 4; ++rr) {
                int r = mi * 16 + g * 4 + rr;
                N_[r * 256 + ((col >> 3) ^ (r & 7)) * 8 + (col & 7)] =
                    f2h(gacc[mi][j][rr]);
            }
        }
    __syncthreads();   // B4: G' visible
#pragma unroll
    for (int i = 0; i < 4; ++i) {
        int c = tid + i * 512;
        int r = c >> 5, ph = c & 31;
        uint4 v = ((const uint4*)N_)[r * 32 + ph];
        ((uint4*)(Gout + (size_t)(base + r) * 256))[ph ^ (r & 7)] = v;
    }
}

extern "C" void kernel_launch(void* const* d_in, const int* in_sizes, int n_in,
                              void* d_out, int out_size, void* d_ws, size_t ws_size,
                              hipStream_t stream) {
    const float* input_bond    = (const float*)d_in[1];
    const int*   atom_graph    = (const int*)d_in[2];
    const int*   bond_graph    = (const int*)d_in[3];
    const int*   num_nbs       = (const int*)d_in[4];
    const float* atom_features = (const float*)d_in[5];
    const float* W2 = (const float*)d_in[6];
    const float* b2 = (const float*)d_in[7];
    const float* W1 = (const float*)d_in[8];
    const float* b1 = (const float*)d_in[9];
    float* out = (float*)d_out;

    char* w = (char*)d_ws;
    u16* f0  = (u16*)w;                          // 16MB
    u16* f1  = (u16*)(w + ((size_t)16 << 20));   // 16MB
    u16* G0  = (u16*)(w + ((size_t)32 << 20));   // 16MB + zero row
    u16* G1  = (u16*)(w + ((size_t)49 << 20));   // 16MB + zero row
    u16* Hb2 = (u16*)(w + ((size_t)66 << 20));   // 16MB + zero row
    u16* Wp1 = (u16*)(w + ((size_t)83 << 20));            // 256KB
    u16* Wp2 = (u16*)(w + ((size_t)83 << 20) + (512 << 10)); // 128KB
    u32* pk  = (u32*)(w + ((size_t)84 << 20));   // 1.25MB (+2KB stage pad)

    prep<<<14401, 256, 0, stream>>>(input_bond, W2, b2, Hb2, atom_graph,
                                    bond_graph, num_nbs, pk, atom_features,
                                    f0, W1, Wp1, Wp2, G0, G1, out);

    // G0 = F0 @ W2a  (skip-mode)
    mega<<<ROWS / BM, 512, 0, stream>>>(f0, nullptr, nullptr, nullptr,
                                        nullptr, nullptr, Wp2, nullptr, G0,
                                        nullptr);
    // depth 0..2 (G ping-pong; final depth: fused row-sum -> d_out)
    mega<<<ROWS / BM, 512, 0, stream>>>(f0, G0, Hb2, pk, Wp1, b1, Wp2, f1, G1,
                                        nullptr);
    mega<<<ROWS / BM, 512, 0, stream>>>(f1, G1, Hb2, pk, Wp1, b1, Wp2, f0, G0,
                                        nullptr);
    mega<<<ROWS / BM, 512, 0, stream>>>(f0, G0, Hb2, pk, Wp1, b1, Wp2, nullptr,
                                        nullptr, out);
}

// Round 25
// 116.384 us; speedup vs baseline: 1.2249x; 1.1761x over previous
//
#include <hip/hip_runtime.h>

// WL_DiffNet, round 25: round-21/24 (best, 136.4-136.9us) + count-dispatched
// gather.
//   num_nbs ~ U[0,10] (mean 5) but gather always issued 10 neighbor-pairs;
//   invalid ones hit ZROW -- L2-trivial but they occupy the LATENCY chain.
//   Count is wave-uniform -> scalar switch(nn) -> templated fully-unrolled
//   grow<CNT> keeps batched loads (no divergence, no variable serial loop).
//   Avg loads/row 20 -> 10. Skipped terms are exact fp16 zeros -> bit-
//   identical math (absmax must stay 0.03125).

#define BB 64
#define NN 512
#define MAXNB 10
#define HH 256
#define ROWS (BB*NN)   // 32768
#define BM 64          // rows per block
#define ZROW 32768     // zero row index in G/Hb2 buffers

typedef _Float16 f16x8 __attribute__((ext_vector_type(8)));
typedef _Float16 h2 __attribute__((ext_vector_type(2)));
typedef __attribute__((ext_vector_type(4))) float f32x4;
typedef unsigned short u16;
typedef unsigned int u32;
typedef __attribute__((address_space(3))) u32 lds_u32;
typedef __attribute__((address_space(1))) const u32 glb_u32;

union U32H2 { u32 u; h2 h; };

__device__ __forceinline__ u16 f2h(float f) {   // rne f32->f16
    union { _Float16 h; u16 u; } v; v.h = (_Float16)f; return v.u;
}
__device__ __forceinline__ void gl16(const u16* g, u16* l) {
    __builtin_amdgcn_global_load_lds((glb_u32*)g, (lds_u32*)l, 16, 0, 0);
}
// XCD-bijective swizzle (nwg % 8 == 0)
__device__ __forceinline__ int xcd_swz(int bid, int nwg) {
    return (bid & 7) * (nwg >> 3) + (bid >> 3);
}

// batched gather for one row with compile-time neighbor count
template <int CNT>
__device__ __forceinline__ void grow(const uint2* __restrict__ Gb,
                                     const uint2* __restrict__ Hb,
                                     const u32* pkRow, int lane,
                                     h2& accA, h2& accB) {
    uint2 ga[CNT], hb[CNT];
#pragma unroll
    for (int k = 0; k < CNT; ++k) {
        u32 p = (u32)__builtin_amdgcn_readfirstlane((int)pkRow[k]);
        ga[k] = Gb[(size_t)(p & 0xffffu) * 64 + lane];
        hb[k] = Hb[(size_t)(p >> 16) * 64 + lane];
    }
    h2 zz = (h2)(_Float16)0;
#pragma unroll
    for (int k = 0; k < CNT; ++k) {
        U32H2 ax{ga[k].x}, ay{ga[k].y}, cx{hb[k].x}, cy{hb[k].y};
        accA += __builtin_elementwise_max(ax.h + cx.h, zz);
        accB += __builtin_elementwise_max(ay.h + cy.h, zz);
    }
}

// ---- prep: hb2 | pkk | castk | wpk1 | wpk2 | zrow+out-zero | pkc ---------
// grid 14529 x 256

__global__ __launch_bounds__(256) void prep(const float* __restrict__ bond,
                                            const float* __restrict__ W2,
                                            const float* __restrict__ b2,
                                            u16* __restrict__ Hb2,
                                            const int* __restrict__ agr,
                                            const int* __restrict__ bgr,
                                            const int* __restrict__ nnb,
                                            u32* __restrict__ pk,
                                            const float* __restrict__ af32,
                                            u16* __restrict__ f0,
                                            const float* __restrict__ W1,
                                            u16* __restrict__ Wp1,
                                            u16* __restrict__ Wp2,
                                            u16* __restrict__ G0,
                                            u16* __restrict__ G1,
                                            float* __restrict__ osum,
                                            u32* __restrict__ pkc) {
    int b = blockIdx.x, tid = threadIdx.x;
    if (b < 4096) {                       // hb2: rows b*8 .. +8
        int c = tid, r0 = b * 8;
        float w[5];
#pragma unroll
        for (int f = 0; f < 5; ++f) w[f] = W2[(size_t)(HH + f) * HH + c];
        float bb = b2[c];
        for (int r = r0; r < r0 + 8; ++r) {
            float s = bb;
#pragma unroll
            for (int f = 0; f < 5; ++f) s += bond[r * 5 + f] * w[f];
            Hb2[(size_t)r * HH + c] = f2h(s);
        }
    } else if (b < 5376) {                // pkk: t < 327680
        int t = (b - 4096) * 256 + tid;
        int r = t / 10, k = t - r * 10;
        int brow = (r >> 9) << 9;
        bool valid = (k < nnb[r]);
        u32 pA = valid ? (u32)(brow + agr[t * 2 + 1]) : (u32)ZROW;
        u32 pB = valid ? (u32)(brow + bgr[t * 2 + 1]) : (u32)ZROW;
        pk[t] = pA | (pB << 16);
    } else if (b < 13568) {               // castk: 8192 blocks, 4 f32/thread
        int i = (b - 5376) * 256 + tid;
        float4 v = ((const float4*)af32)[i];
        u32 a = f2h(v.x) | ((u32)f2h(v.y) << 16);
        u32 c = f2h(v.z) | ((u32)f2h(v.w) << 16);
        ((uint2*)f0)[i] = make_uint2(a, c);
    } else if (b < 14080) {               // wpk1: W1 [512x256] -> Wp1
        int o = (b - 13568) * 256 + tid;
        int e = o & 7, lane = (o >> 3) & 63, nq = (o >> 9) & 15, kt = o >> 13;
        int k = kt * 32 + (lane >> 4) * 8 + e;
        int n = nq * 16 + (lane & 15);
        Wp1[o] = f2h(W1[(size_t)k * HH + n]);
    } else if (b < 14336) {               // wpk2: W2a [256x256] -> Wp2
        int o = (b - 14080) * 256 + tid;
        int e = o & 7, lane = (o >> 3) & 63, nq = (o >> 9) & 15, kt = o >> 13;
        int k = kt * 32 + (lane >> 4) * 8 + e;
        int n = nq * 16 + (lane & 15);
        Wp2[o] = f2h(W2[(size_t)k * HH + n]);
    } else if (b == 14336) {              // zrow
        G0[(size_t)ZROW * 256 + tid] = 0;
        G1[(size_t)ZROW * 256 + tid] = 0;
        Hb2[(size_t)ZROW * 256 + tid] = 0;
    } else if (b < 14401) {               // zero d_out: 64 blocks
        osum[(b - 14337) * 256 + tid] = 0.f;
    } else {                              // pkc: per-row neighbor count
        int i = (b - 14401) * 256 + tid;  // < 32768
        int nn = nnb[i];
        pkc[i] = (u32)(nn < 0 ? 0 : (nn > MAXNB ? MAXNB : nn));
    }
}

// ---- mega: fused gather + [F|N]@W1 + F'@W2a ------------------------------
// 512 thr, 8 waves; wave wc owns cols wc*32..+32, all 64 rows.
// LDS: A_ 32KB (F -> F') + N_ 32KB (N -> G') + pkL 3KB + pkLc 1KB.

__global__ __launch_bounds__(512, 4) void mega(const u16* __restrict__ Fh,
                                               const u16* __restrict__ Gall,
                                               const u16* __restrict__ Hall,
                                               const u32* __restrict__ pk,
                                               const u32* __restrict__ pkc,
                                               const u16* __restrict__ Wp1,
                                               const float* __restrict__ b1,
                                               const u16* __restrict__ Wp2,
                                               u16* __restrict__ Fout,
                                               u16* __restrict__ Gout,
                                               float* __restrict__ osum) {
    __shared__ u16 A_[BM * 256];   // 32KB
    __shared__ u16 N_[BM * 256];   // 32KB
    __shared__ u32 pkL[768];       // 3KB (640 used; staged in 3x1KB gl16)
    __shared__ u32 pkLc[256];      // 1KB (64 used; 1x1KB gl16)

    int tid = threadIdx.x;
    int base = xcd_swz(blockIdx.x, gridDim.x) * BM;
    int lane = tid & 63, wid = tid >> 6;
    int wc = wid, m = lane & 15, g = lane >> 4;

    // stage F -> A_ (async, pre-swizzled PER-LANE source / linear dest)
#pragma unroll
    for (int q = 0; q < 4; ++q) {
        int c = (wid * 4 + q) * 64 + lane;
        int r = c >> 5, ph = c & 31;
        gl16(Fh + (size_t)(base + r) * 256 + (ph ^ (r & 7)) * 8,
             A_ + (wid * 4 + q) * 512);
    }
    // stage pk slice -> pkL (waves 0..2) and counts -> pkLc (wave 3)
    if (Wp1 && wid < 3)
        gl16((const u16*)(pk + (size_t)base * 10) + wid * 512 + lane * 8,
             (u16*)pkL + wid * 512);
    if (Wp1 && wid == 3)
        gl16((const u16*)(pkc + (size_t)base) + lane * 8, (u16*)pkLc);

    uint4 breg[2];
    // prefetch B kt0 (latency absorbed by barrier0's drain)
    {
        const u16* Wp0 = Wp1 ? Wp1 : Wp2;
#pragma unroll
        for (int j = 0; j < 2; ++j)
            breg[j] = *(const uint4*)(Wp0 + ((size_t)(wc * 2 + j) * 64 + lane) * 8);
    }
    __syncthreads();   // barrier0: A_ + pkL + pkLc staged

    if (Wp1) {
        // ---- gather: rows wid*8..+8; count-dispatched batched loads ------
        const uint2* Gb = (const uint2*)Gall;
        const uint2* Hb = (const uint2*)Hall;
        h2 zz = (h2)(_Float16)0;
#pragma unroll
        for (int i = 0; i < 8; ++i) {
            int r = wid * 8 + i;
            int nn = __builtin_amdgcn_readfirstlane((int)pkLc[r]);
            const u32* pkRow = pkL + r * 10;
            h2 accA = zz, accB = zz;
            switch (nn) {    // wave-uniform scalar branch, no divergence
            case 1:  grow<1>(Gb, Hb, pkRow, lane, accA, accB); break;
            case 2:  grow<2>(Gb, Hb, pkRow, lane, accA, accB); break;
            case 3:  grow<3>(Gb, Hb, pkRow, lane, accA, accB); break;
            case 4:  grow<4>(Gb, Hb, pkRow, lane, accA, accB); break;
            case 5:  grow<5>(Gb, Hb, pkRow, lane, accA, accB); break;
            case 6:  grow<6>(Gb, Hb, pkRow, lane, accA, accB); break;
            case 7:  grow<7>(Gb, Hb, pkRow, lane, accA, accB); break;
            case 8:  grow<8>(Gb, Hb, pkRow, lane, accA, accB); break;
            case 9:  grow<9>(Gb, Hb, pkRow, lane, accA, accB); break;
            case 10: grow<10>(Gb, Hb, pkRow, lane, accA, accB); break;
            default: break;  // nn == 0
            }
            U32H2 oa, ob; oa.h = accA; ob.h = accB;
            int s16 = (lane >> 1) ^ (r & 7);
            *(uint2*)(N_ + r * 256 + s16 * 8 + (lane & 1) * 4) =
                make_uint2(oa.u, ob.u);
        }

        f32x4 acc[4][2];
#pragma unroll
        for (int mi = 0; mi < 4; ++mi)
#pragma unroll
            for (int j = 0; j < 2; ++j) acc[mi][j] = (f32x4){0.f, 0.f, 0.f, 0.f};

        // ---- phase-1a: kt 0..7 reads A_ ONLY -- no barrier after gather
        for (int kt = 0; kt < 8; ++kt) {
            f16x8 bcur[2];
            bcur[0] = *(f16x8*)&breg[0];
            bcur[1] = *(f16x8*)&breg[1];
#pragma unroll
            for (int j = 0; j < 2; ++j)
                breg[j] = *(const uint4*)(Wp1 +
                    ((size_t)((kt + 1) * 16 + wc * 2 + j) * 64 + lane) * 8);
            int asl = kt * 4 + g;
            f16x8 af[4];
#pragma unroll
            for (int mi = 0; mi < 4; ++mi) {
                int r = mi * 16 + m;
                af[mi] = *(const f16x8*)(A_ + r * 256 + ((asl ^ (r & 7)) * 8));
            }
#pragma unroll
            for (int mi = 0; mi < 4; ++mi)
#pragma unroll
                for (int j = 0; j < 2; ++j)
                    acc[mi][j] = __builtin_amdgcn_mfma_f32_16x16x32_f16(
                        af[mi], bcur[j], acc[mi][j], 0, 0, 0);
        }
        __syncthreads();   // barrier1: all N_ writes visible

        // ---- phase-1b: kt 8..15 reads N_
        for (int kt = 8; kt < 16; ++kt) {
            f16x8 bcur[2];
            bcur[0] = *(f16x8*)&breg[0];
            bcur[1] = *(f16x8*)&breg[1];
            if (kt < 15) {
#pragma unroll
                for (int j = 0; j < 2; ++j)
                    breg[j] = *(const uint4*)(Wp1 +
                        ((size_t)((kt + 1) * 16 + wc * 2 + j) * 64 + lane) * 8);
            } else if (Gout) {
#pragma unroll
                for (int j = 0; j < 2; ++j)
                    breg[j] = *(const uint4*)(Wp2 +
                        ((size_t)(wc * 2 + j) * 64 + lane) * 8);
            }
            int asl = (kt & 7) * 4 + g;
            f16x8 af[4];
#pragma unroll
            for (int mi = 0; mi < 4; ++mi) {
                int r = mi * 16 + m;
                af[mi] = *(const f16x8*)(N_ + r * 256 + ((asl ^ (r & 7)) * 8));
            }
#pragma unroll
            for (int mi = 0; mi < 4; ++mi)
#pragma unroll
                for (int j = 0; j < 2; ++j)
                    acc[mi][j] = __builtin_amdgcn_mfma_f32_16x16x32_f16(
                        af[mi], bcur[j], acc[mi][j], 0, 0, 0);
        }

        if (osum) {
            // final depth: relu(acc+b1), in-register row-sum, reduce over g,
            // one atomicAdd per (block, col). No F' store, no phase-2.
            int b = base >> 9;
#pragma unroll
            for (int j = 0; j < 2; ++j) {
                int col = wc * 32 + j * 16 + m;
                float bb = b1[col];
                float s = 0.f;
#pragma unroll
                for (int mi = 0; mi < 4; ++mi)
#pragma unroll
                    for (int rr = 0; rr < 4; ++rr)
                        s += fmaxf(acc[mi][j][rr] + bb, 0.f);
                s += __shfl_xor(s, 16);
                s += __shfl_xor(s, 32);
                if (g == 0) atomicAdd(osum + b * 256 + col, s);
            }
            return;
        }

        __syncthreads();   // B2: all waves done reading A_/N_

        // F' = relu(acc+b1) -> A_ (F dead)
#pragma unroll
        for (int mi = 0; mi < 4; ++mi)
#pragma unroll
            for (int j = 0; j < 2; ++j) {
                int col = wc * 32 + j * 16 + m;
                float bb = b1[col];
#pragma unroll
                for (int rr = 0; rr < 4; ++rr) {
                    int r = mi * 16 + g * 4 + rr;
                    A_[r * 256 + ((col >> 3) ^ (r & 7)) * 8 + (col & 7)] =
                        f2h(fmaxf(acc[mi][j][rr] + bb, 0.f));
                }
            }
        __syncthreads();   // B3: F' visible

        // coalesced F' store
#pragma unroll
        for (int i = 0; i < 4; ++i) {
            int c = tid + i * 512;
            int r = c >> 5, ph = c & 31;
            uint4 v = ((const uint4*)A_)[r * 32 + ph];
            ((uint4*)(Fout + (size_t)(base + r) * 256))[ph ^ (r & 7)] = v;
        }
    }
    // (skip-mode: barrier0 already done; breg holds Wp2 kt0)

    if (!Gout) return;

    // phase-2: G' = A_(F' or F) @ W2a, K=256, 8 kt, barrier-free
    f32x4 gacc[4][2];
#pragma unroll
    for (int mi = 0; mi < 4; ++mi)
#pragma unroll
        for (int j = 0; j < 2; ++j) gacc[mi][j] = (f32x4){0.f, 0.f, 0.f, 0.f};

    for (int kt = 0; kt < 8; ++kt) {
        f16x8 bcur[2];
        bcur[0] = *(f16x8*)&breg[0];
        bcur[1] = *(f16x8*)&breg[1];
        if (kt < 7) {
#pragma unroll
            for (int j = 0; j < 2; ++j)
                breg[j] = *(const uint4*)(Wp2 +
                    ((size_t)((kt + 1) * 16 + wc * 2 + j) * 64 + lane) * 8);
        }
        int asl = kt * 4 + g;
        f16x8 af[4];
#pragma unroll
        for (int mi = 0; mi < 4; ++mi) {
            int r = mi * 16 + m;
            af[mi] = *(const f16x8*)(A_ + r * 256 + ((asl ^ (r & 7)) * 8));
        }
#pragma unroll
        for (int mi = 0; mi < 4; ++mi)
#pragma unroll
            for (int j = 0; j < 2; ++j)
                gacc[mi][j] = __builtin_amdgcn_mfma_f32_16x16x32_f16(
                    af[mi], bcur[j], gacc[mi][j], 0, 0, 0);
    }

    // G' -> N_ bounce (N dead), then coalesced store
#pragma unroll
    for (int mi = 0; mi < 4; ++mi)
#pragma unroll
        for (int j = 0; j < 2; ++j) {
            int col = wc * 32 + j * 16 + m;
#pragma unroll
            for (int rr = 0; rr < 4; ++rr) {
                int r = mi * 16 + g * 4 + rr;
                N_[r * 256 + ((col >> 3) ^ (r & 7)) * 8 + (col & 7)] =
                    f2h(gacc[mi][j][rr]);
            }
        }
    __syncthreads();   // B4: G' visible
#pragma unroll
    for (int i = 0; i < 4; ++i) {
        int c = tid + i * 512;
        int r = c >> 5, ph = c & 31;
        uint4 v = ((const uint4*)N_)[r * 32 + ph];
        ((uint4*)(Gout + (size_t)(base + r) * 256))[ph ^ (r & 7)] = v;
    }
}

extern "C" void kernel_launch(void* const* d_in, const int* in_sizes, int n_in,
                              void* d_out, int out_size, void* d_ws, size_t ws_size,
                              hipStream_t stream) {
    const float* input_bond    = (const float*)d_in[1];
    const int*   atom_graph    = (const int*)d_in[2];
    const int*   bond_graph    = (const int*)d_in[3];
    const int*   num_nbs       = (const int*)d_in[4];
    const float* atom_features = (const float*)d_in[5];
    const float* W2 = (const float*)d_in[6];
    const float* b2 = (const float*)d_in[7];
    const float* W1 = (const float*)d_in[8];
    const float* b1 = (const float*)d_in[9];
    float* out = (float*)d_out;

    char* w = (char*)d_ws;
    u16* f0  = (u16*)w;                          // 16MB
    u16* f1  = (u16*)(w + ((size_t)16 << 20));   // 16MB
    u16* G0  = (u16*)(w + ((size_t)32 << 20));   // 16MB + zero row
    u16* G1  = (u16*)(w + ((size_t)49 << 20));   // 16MB + zero row
    u16* Hb2 = (u16*)(w + ((size_t)66 << 20));   // 16MB + zero row
    u16* Wp1 = (u16*)(w + ((size_t)83 << 20));            // 256KB
    u16* Wp2 = (u16*)(w + ((size_t)83 << 20) + (512 << 10)); // 128KB
    u32* pk  = (u32*)(w + ((size_t)84 << 20));   // 1.25MB (+pad)
    u32* pkc = (u32*)(w + ((size_t)86 << 20));   // 128KB + 1KB stage pad

    prep<<<14529, 256, 0, stream>>>(input_bond, W2, b2, Hb2, atom_graph,
                                    bond_graph, num_nbs, pk, atom_features,
                                    f0, W1, Wp1, Wp2, G0, G1, out, pkc);

    // G0 = F0 @ W2a  (skip-mode)
    mega<<<ROWS / BM, 512, 0, stream>>>(f0, nullptr, nullptr, nullptr, nullptr,
                                        nullptr, nullptr, Wp2, nullptr, G0,
                                        nullptr);
    // depth 0..2 (G ping-pong; final depth: fused row-sum -> d_out)
    mega<<<ROWS / BM, 512, 0, stream>>>(f0, G0, Hb2, pk, pkc, Wp1, b1, Wp2,
                                        f1, G1, nullptr);
    mega<<<ROWS / BM, 512, 0, stream>>>(f1, G1, Hb2, pk, pkc, Wp1, b1, Wp2,
                                        f0, G0, nullptr);
    mega<<<ROWS / BM, 512, 0, stream>>>(f0, G0, Hb2, pk, pkc, Wp1, b1, Wp2,
                                        nullptr, nullptr, out);
}